// Round 6
// baseline (496.869 us; speedup 1.0000x reference)
//
#include <hip/hip_runtime.h>

// DecoderLSTM: B=4096, T=128 (127 steps), H=128, 4H=512, V=30, E=256.
// R6: 512 blocks x 8 rows -> 2 independent blocks/CU so barrier stalls of one
// block are filled by the other (R5 was 1 block/CU, latency-exposed).
// M=8 on 16x16x32 MFMA: valid C-rows live in lane-quads 0-1 only, so after
// the MFMA chain 8 __shfl ops redistribute p={2,3} gate cells to quads 2-3 -
// every lane does exactly 2 pointwise cells (keeps per-CU transcendental
// issue at the floor). hbuf rows 8-15 zeroed once (garbage rows row-isolated).
// Else structure = R5: 9 waves, wave 8 does logits+transpose-softmax+CE one
// step behind, ONE barrier/step, W-frags in branch-exclusive register union.

typedef __bf16 bf16x8 __attribute__((ext_vector_type(8)));
typedef float  f32x4  __attribute__((ext_vector_type(4)));

namespace {
constexpr int Bn = 4096, Tn = 128, Vn = 30, En = 256, Hn = 128, Gn = 512;
constexpr int WS_LOSS  = 0;
constexpr int WS_MASK  = 1;
constexpr int WS_CNT   = 2;
constexpr int WS_XPROJ = 16;                  // 30*512 fp32, layout [v][k][g]
constexpr int WS_WF_F  = WS_XPROJ + Vn * Gn;  // 65536 bf16 Whh-frags + 4096 bf16 Wlin-frags
constexpr int NBLK = 512;                     // 8 rows per block
}

__device__ __forceinline__ float fexp2(float x) { return __builtin_amdgcn_exp2f(x); }
__device__ __forceinline__ float frcp(float x)  { return __builtin_amdgcn_rcpf(x); }
__device__ __forceinline__ float sigf(float x)  { return frcp(1.f + fexp2(x * -1.44269504f)); }
__device__ __forceinline__ float tanh_(float x) { return 1.f - 2.f * frcp(fexp2(x * 2.88539008f) + 1.f); }

// ---- setup, 94 blocks x 256 (unchanged; zeroes loss/mask/cnt)
__global__ void k_setup(const float* __restrict__ emb, const float* __restrict__ W_ih,
                        const float* __restrict__ b_ih, const float* __restrict__ b_hh,
                        const float* __restrict__ W_hh, const float* __restrict__ W_lin,
                        float* __restrict__ ws) {
  const int bid = blockIdx.x, tid = threadIdx.x;
  if (bid < 60) {
    __shared__ __align__(16) float es[En];
    int v = bid >> 1;
    int j = ((bid & 1) << 8) + tid;   // j = g*128 + k
    es[tid] = emb[v * En + tid];
    __syncthreads();
    float a = b_ih[j] + b_hh[j];
    const float* wr = W_ih + j * En;
#pragma unroll 4
    for (int e = 0; e < En; e += 4) {
      float4 w = *(const float4*)(wr + e);
      float4 x = *(const float4*)(es + e);
      a += x.x * w.x + x.y * w.y + x.z * w.z + x.w * w.w;
    }
    ws[WS_XPROJ + v * Gn + (j & 127) * 4 + (j >> 7)] = a;
  } else if (bid < 92) {
    int fid = (bid - 60) * 256 + tid;  // 0..8191
    int l = fid & 63, kt = (fid >> 6) & 3, g = (fid >> 8) & 3, w = fid >> 10;
    int n  = (g * 8 + w) * 16 + (l & 15);
    int k0 = kt * 32 + (l >> 4) * 8;
    const float* src = W_hh + n * Hn + k0;
    union { __bf16 h[8]; uint4 u; } pk;
#pragma unroll
    for (int j = 0; j < 8; ++j) pk.h[j] = (__bf16)src[j];
    __bf16* wf = (__bf16*)(ws + WS_WF_F);
    *(uint4*)(wf + fid * 8) = pk.u;
  } else {
    int fid = (bid - 92) * 256 + tid;  // 0..511
    if (fid < 3) ws[fid] = 0.f;        // WS_LOSS, WS_MASK, WS_CNT
    int l = fid & 63, kt = (fid >> 6) & 3, n = fid >> 8;
    int col = n * 16 + (l & 15);
    int k0  = kt * 32 + (l >> 4) * 8;
    union { __bf16 h[8]; uint4 u; } pk;
#pragma unroll
    for (int j = 0; j < 8; ++j)
      pk.h[j] = (col < Vn) ? (__bf16)W_lin[col * Hn + k0 + j] : (__bf16)0.f;
    __bf16* wf = (__bf16*)(ws + WS_WF_F);
    *(uint4*)(wf + 65536 + fid * 8) = pk.u;
  }
}

// ---- main: 512 blocks x 576 threads (9 waves), 8 batch rows/block
__global__ __launch_bounds__(576, 4) void k_main(
    const int* __restrict__ inpt, const float* __restrict__ h0,
    const float* __restrict__ c0, const float* __restrict__ maskY,
    const float* __restrict__ b_lin, float* __restrict__ ws,
    float* __restrict__ out) {
  __shared__ __align__(16) __bf16 hbuf[2][16][136];  // rows 8-15 zeroed once
  __shared__ int   tokL[8 * 129];
  __shared__ float maskL[8 * 132];
  __shared__ __align__(16) float logits[8 * 36];
  __shared__ float red[2];

  const float4* X4  = (const float4*)(ws + WS_XPROJ); // [v*128 + k] -> (i,f,g,o)
  const __bf16* wf  = (const __bf16*)(ws + WS_WF_F);
  const __bf16* wlf = wf + 65536;

  const int tid = threadIdx.x;
  const int w = tid >> 6, l = tid & 63, quad = l >> 4, lc = l & 15;
  const int row0 = blockIdx.x * 8;
  const int kh = w * 16 + lc;
  // pointwise row ownership: q0->{0,1}, q1->{4,5}, q2->{2,3}, q3->{6,7}
  const int prow0 = (quad < 2) ? quad * 4 : (quad - 2) * 4 + 2;

  // staging (all 9 waves)
  for (int idx = tid; idx < 8 * Tn; idx += 576) {
    int r = idx >> 7, t = idx & 127;
    tokL[r * 129 + t]  = inpt[(row0 + r) * Tn + t];
    maskL[r * 132 + t] = maskY[(row0 + r) * Tn + t];
  }
  for (int idx = tid; idx < 8 * Hn; idx += 576) {
    int r = idx >> 7, k = idx & 127;
    hbuf[0][r][k] = (__bf16)h0[(row0 + r) * Hn + k];
  }
  for (int idx = tid; idx < 2 * 8 * 136; idx += 576) {  // zero rows 8-15, both bufs
    int pr = idx / (8 * 136), rem = idx - pr * (8 * 136);
    hbuf[pr][8 + rem / 136][rem % 136] = (__bf16)0.f;
  }

  // weight fragments: branch-exclusive union (cores: W_hh[4][4]; wave8: W_lin[2][4])
  bf16x8 wreg[4][4];
  float  creg[2];
  float  bias0 = 0.f, bias1 = 0.f, mloc = 0.f;
  if (w < 8) {
#pragma unroll
    for (int g = 0; g < 4; ++g)
#pragma unroll
      for (int kt = 0; kt < 4; ++kt)
        wreg[g][kt] = __builtin_bit_cast(
            bf16x8, *(const uint4*)(wf + (((w * 4 + g) * 4 + kt) * 64 + l) * 8));
#pragma unroll
    for (int p = 0; p < 2; ++p)
      creg[p] = c0[(row0 + prow0 + p) * Hn + kh];
    if (w == 7) {  // block-local mask sum: 8 rows x 128 = 256 float4
      float s = 0.f;
      const float4* m4 = (const float4*)(maskY + row0 * Tn);
#pragma unroll
      for (int i = 0; i < 4; ++i) s += m4[l + i * 64].x + m4[l + i * 64].y +
                                       m4[l + i * 64].z + m4[l + i * 64].w;
      mloc = s;
    }
  } else {
#pragma unroll
    for (int n = 0; n < 2; ++n)
#pragma unroll
      for (int kt = 0; kt < 4; ++kt)
        wreg[n][kt] = __builtin_bit_cast(
            bf16x8, *(const uint4*)(wlf + ((n * 4 + kt) * 64 + l) * 8));
    bias0 = b_lin[lc];
    bias1 = (lc < Vn - 16) ? b_lin[lc + 16] : -1e30f;
  }
  float ce_acc = 0.f;
  __syncthreads();

  // Xproj preload for t=0 (cores, quads 0-1 hold the valid C-rows)
  float4 xv[4];
  if (w < 8 && quad < 2) {
#pragma unroll
    for (int p = 0; p < 4; ++p)
      xv[p] = X4[tokL[(quad * 4 + p) * 129] * 128 + kh];
  }

  for (int t = 0; t < Tn; ++t) {  // cores act t<127, wave8 acts t>=1
    const int par = t & 1;
    const __bf16* hc = &hbuf[par][0][0];
    __bf16*       hn = &hbuf[par ^ 1][0][0];

    if (w < 8) {
      if (t < Tn - 1) {
        bf16x8 af[4];
#pragma unroll
        for (int kt = 0; kt < 4; ++kt)
          af[kt] = __builtin_bit_cast(
              bf16x8, *(const uint4*)(hc + lc * 136 + kt * 32 + quad * 8));

        int tk[4];
        if (quad < 2) {
#pragma unroll
          for (int p = 0; p < 4; ++p) tk[p] = tokL[(quad * 4 + p) * 129 + t + 1];
        }

        f32x4 acc[4];
#pragma unroll
        for (int p = 0; p < 4; ++p) {
          float4 x = (quad < 2) ? xv[p] : float4{0.f, 0.f, 0.f, 0.f};
          acc[0][p] = x.x; acc[1][p] = x.y; acc[2][p] = x.z; acc[3][p] = x.w;
        }
#pragma unroll
        for (int g = 0; g < 4; ++g)
#pragma unroll
          for (int kt = 0; kt < 4; ++kt)
            acc[g] = __builtin_amdgcn_mfma_f32_16x16x32_bf16(af[kt], wreg[g][kt], acc[g], 0, 0, 0);

        // prefetch Xproj for t+1
        float4 xn[4];
        if (quad < 2) {
#pragma unroll
          for (int p = 0; p < 4; ++p) xn[p] = X4[tk[p] * 128 + kh];
        }

        // redistribute p={2,3} cells: quad q -> quad q+2 (8 shfls)
        float mv[4][2];
#pragma unroll
        for (int g = 0; g < 4; ++g)
#pragma unroll
          for (int pp = 0; pp < 2; ++pp)
            mv[g][pp] = __shfl(acc[g][2 + pp], l & 31);

#pragma unroll
        for (int p = 0; p < 2; ++p) {
          float gi = (quad < 2) ? acc[0][p] : mv[0][p];
          float gf = (quad < 2) ? acc[1][p] : mv[1][p];
          float gg = (quad < 2) ? acc[2][p] : mv[2][p];
          float go = (quad < 2) ? acc[3][p] : mv[3][p];
          float c2 = sigf(gf) * creg[p] + sigf(gi) * tanh_(gg);
          float h2 = sigf(go) * tanh_(c2);
          creg[p] = c2;
          hn[(prow0 + p) * 136 + kh] = (__bf16)h2;
        }
#pragma unroll
        for (int p = 0; p < 4; ++p) xv[p] = xn[p];
      }
    } else if (t >= 1) {
      // logits of h(t) -> CE for ref-step t-1; targets tok[:,t], mask[:,t-1]
      bf16x8 af[4];
#pragma unroll
      for (int kt = 0; kt < 4; ++kt)
        af[kt] = __builtin_bit_cast(
            bf16x8, *(const uint4*)(hc + lc * 136 + kt * 32 + quad * 8));
      f32x4 lacc[2] = {{bias0, bias0, bias0, bias0}, {bias1, bias1, bias1, bias1}};
#pragma unroll
      for (int kt = 0; kt < 4; ++kt) {
        lacc[0] = __builtin_amdgcn_mfma_f32_16x16x32_bf16(af[kt], wreg[0][kt], lacc[0], 0, 0, 0);
        lacc[1] = __builtin_amdgcn_mfma_f32_16x16x32_bf16(af[kt], wreg[1][kt], lacc[1], 0, 0, 0);
      }
      if (quad < 2) {
#pragma unroll
        for (int p = 0; p < 4; ++p) {
          logits[(quad * 4 + p) * 36 + lc]      = lacc[0][p];
          logits[(quad * 4 + p) * 36 + 16 + lc] = lacc[1][p];
        }
      }
      // transpose-softmax: lanes 0-31, 4 lanes/row, 8 logits each, 2 shfl rounds
      if (l < 32) {
        int row = l >> 2, j = l & 3;
        float4 v0 = *(const float4*)(logits + row * 36 + j * 8);
        float4 v1 = *(const float4*)(logits + row * 36 + j * 8 + 4);
        float m = fmaxf(fmaxf(fmaxf(v0.x, v0.y), fmaxf(v0.z, v0.w)),
                        fmaxf(fmaxf(v1.x, v1.y), fmaxf(v1.z, v1.w)));
        m = fmaxf(m, __shfl_xor(m, 1));
        m = fmaxf(m, __shfl_xor(m, 2));
        float e = fexp2((v0.x - m) * 1.44269504f) + fexp2((v0.y - m) * 1.44269504f) +
                  fexp2((v0.z - m) * 1.44269504f) + fexp2((v0.w - m) * 1.44269504f) +
                  fexp2((v1.x - m) * 1.44269504f) + fexp2((v1.y - m) * 1.44269504f) +
                  fexp2((v1.z - m) * 1.44269504f) + fexp2((v1.w - m) * 1.44269504f);
        e += __shfl_xor(e, 1);
        e += __shfl_xor(e, 2);
        if (j == 0) {
          int   y  = tokL[row * 129 + t];
          float ly = logits[row * 36 + y];
          float ce = (m + __logf(e)) - ly;
          ce_acc += ce * maskL[row * 132 + t - 1];
        }
      }
    }
    __syncthreads();  // the only barrier per step
  }

  // final reductions: wave 7 mask partial -> LDS; wave 8 reduces CE + finishes
  if (w == 7) {
#pragma unroll
    for (int off = 32; off > 0; off >>= 1) mloc += __shfl_down(mloc, off);
    if (l == 0) red[0] = mloc;
  }
  __syncthreads();
  if (w == 8) {
#pragma unroll
    for (int off = 32; off > 0; off >>= 1) ce_acc += __shfl_down(ce_acc, off);
    if (l == 0) {
      atomicAdd(ws + WS_LOSS, ce_acc);
      atomicAdd(ws + WS_MASK, red[0]);
      __threadfence();
      unsigned old = atomicAdd((unsigned*)(ws + WS_CNT), 1u);
      if (old == NBLK - 1) {  // last block publishes
        float lv = atomicAdd(ws + WS_LOSS, 0.f);
        float mv2 = atomicAdd(ws + WS_MASK, 0.f);
        out[0] = lv / mv2;
      }
    }
  }
}

extern "C" void kernel_launch(void* const* d_in, const int* in_sizes, int n_in,
                              void* d_out, int out_size, void* d_ws, size_t ws_size,
                              hipStream_t stream) {
  const int*   inpt  = (const int*)  d_in[0];
  const float* h0    = (const float*)d_in[1];
  const float* c0    = (const float*)d_in[2];
  const float* maskY = (const float*)d_in[3];
  // d_in[4] = beta (unused)
  const float* emb   = (const float*)d_in[5];
  const float* W_ih  = (const float*)d_in[6];
  const float* b_ih  = (const float*)d_in[7];
  const float* W_hh  = (const float*)d_in[8];
  const float* b_hh  = (const float*)d_in[9];
  const float* W_lin = (const float*)d_in[10];
  const float* b_lin = (const float*)d_in[11];
  float* ws  = (float*)d_ws;
  float* out = (float*)d_out;

  hipLaunchKernelGGL(k_setup, dim3(94),   dim3(256), 0, stream,
                     emb, W_ih, b_ih, b_hh, W_hh, W_lin, ws);
  hipLaunchKernelGGL(k_main,  dim3(NBLK), dim3(576), 0, stream,
                     inpt, h0, c0, maskY, b_lin, ws, out);
}

// Round 7
// 397.403 us; speedup vs baseline: 1.2503x; 1.2503x over previous
//
#include <hip/hip_runtime.h>

// DecoderLSTM: B=4096, T=128 (127 steps), H=128, 4H=512, V=30, E=256.
// R7: 512 blocks x 8 rows, targeting 2 co-resident blocks/CU (TLP fills the
// barrier/latency dead time that capped R5). Spill-free by design: R4's lean
// register set (no prefetch regs, no shfl redistribution, no launch_bounds
// min-waves). M=8 on the 16x16x32 MFMA via exec-masking: hbuf rows 8-15 are
// zeroed once and never rewritten; Xproj init, pointwise, logits stores and
// CE are guarded to lane-quads 0-1. Per-wave issue == R5; per-CU issue 2x ->
// fills stalls. Else structure = R5: 9 waves, wave 8 logits+transpose-softmax
// one step behind, ONE barrier/step, branch-exclusive W-frag register union.

typedef __bf16 bf16x8 __attribute__((ext_vector_type(8)));
typedef float  f32x4  __attribute__((ext_vector_type(4)));

namespace {
constexpr int Bn = 4096, Tn = 128, Vn = 30, En = 256, Hn = 128, Gn = 512;
constexpr int WS_LOSS  = 0;
constexpr int WS_MASK  = 1;
constexpr int WS_CNT   = 2;
constexpr int WS_XPROJ = 16;                  // 30*512 fp32, layout [v][k][g]
constexpr int WS_WF_F  = WS_XPROJ + Vn * Gn;  // 65536 bf16 Whh-frags + 4096 bf16 Wlin-frags
constexpr int NBLK = 512;                     // 8 rows per block
}

__device__ __forceinline__ float fexp2(float x) { return __builtin_amdgcn_exp2f(x); }
__device__ __forceinline__ float frcp(float x)  { return __builtin_amdgcn_rcpf(x); }
__device__ __forceinline__ float sigf(float x)  { return frcp(1.f + fexp2(x * -1.44269504f)); }
__device__ __forceinline__ float tanh_(float x) { return 1.f - 2.f * frcp(fexp2(x * 2.88539008f) + 1.f); }

// ---- setup, 94 blocks x 256 (unchanged; zeroes loss/mask/cnt)
__global__ void k_setup(const float* __restrict__ emb, const float* __restrict__ W_ih,
                        const float* __restrict__ b_ih, const float* __restrict__ b_hh,
                        const float* __restrict__ W_hh, const float* __restrict__ W_lin,
                        float* __restrict__ ws) {
  const int bid = blockIdx.x, tid = threadIdx.x;
  if (bid < 60) {
    __shared__ __align__(16) float es[En];
    int v = bid >> 1;
    int j = ((bid & 1) << 8) + tid;   // j = g*128 + k
    es[tid] = emb[v * En + tid];
    __syncthreads();
    float a = b_ih[j] + b_hh[j];
    const float* wr = W_ih + j * En;
#pragma unroll 4
    for (int e = 0; e < En; e += 4) {
      float4 w = *(const float4*)(wr + e);
      float4 x = *(const float4*)(es + e);
      a += x.x * w.x + x.y * w.y + x.z * w.z + x.w * w.w;
    }
    ws[WS_XPROJ + v * Gn + (j & 127) * 4 + (j >> 7)] = a;
  } else if (bid < 92) {
    int fid = (bid - 60) * 256 + tid;  // 0..8191
    int l = fid & 63, kt = (fid >> 6) & 3, g = (fid >> 8) & 3, w = fid >> 10;
    int n  = (g * 8 + w) * 16 + (l & 15);
    int k0 = kt * 32 + (l >> 4) * 8;
    const float* src = W_hh + n * Hn + k0;
    union { __bf16 h[8]; uint4 u; } pk;
#pragma unroll
    for (int j = 0; j < 8; ++j) pk.h[j] = (__bf16)src[j];
    __bf16* wf = (__bf16*)(ws + WS_WF_F);
    *(uint4*)(wf + fid * 8) = pk.u;
  } else {
    int fid = (bid - 92) * 256 + tid;  // 0..511
    if (fid < 3) ws[fid] = 0.f;        // WS_LOSS, WS_MASK, WS_CNT
    int l = fid & 63, kt = (fid >> 6) & 3, n = fid >> 8;
    int col = n * 16 + (l & 15);
    int k0  = kt * 32 + (l >> 4) * 8;
    union { __bf16 h[8]; uint4 u; } pk;
#pragma unroll
    for (int j = 0; j < 8; ++j)
      pk.h[j] = (col < Vn) ? (__bf16)W_lin[col * Hn + k0 + j] : (__bf16)0.f;
    __bf16* wf = (__bf16*)(ws + WS_WF_F);
    *(uint4*)(wf + 65536 + fid * 8) = pk.u;
  }
}

// ---- main: 512 blocks x 576 threads (9 waves), 8 batch rows/block
__global__ __launch_bounds__(576) void k_main(
    const int* __restrict__ inpt, const float* __restrict__ h0,
    const float* __restrict__ c0, const float* __restrict__ maskY,
    const float* __restrict__ b_lin, float* __restrict__ ws,
    float* __restrict__ out) {
  __shared__ __align__(16) __bf16 hbuf[2][16][136];  // rows 8-15 stay zero
  __shared__ int   tokL[8 * 129];
  __shared__ float maskL[8 * 132];
  __shared__ __align__(16) float logits[8 * 36];
  __shared__ float red[2];

  const float4* X4  = (const float4*)(ws + WS_XPROJ); // [v*128 + k] -> (i,f,g,o)
  const __bf16* wf  = (const __bf16*)(ws + WS_WF_F);
  const __bf16* wlf = wf + 65536;

  const int tid = threadIdx.x;
  const int w = tid >> 6, l = tid & 63, quad = l >> 4, lc = l & 15;
  const int row0 = blockIdx.x * 8;
  const int kh = w * 16 + lc;

  // staging (all 9 waves)
  for (int idx = tid; idx < 8 * Tn; idx += 576) {
    int r = idx >> 7, t = idx & 127;
    tokL[r * 129 + t]  = inpt[(row0 + r) * Tn + t];
    maskL[r * 132 + t] = maskY[(row0 + r) * Tn + t];
  }
  for (int idx = tid; idx < 8 * Hn; idx += 576) {
    int r = idx >> 7, k = idx & 127;
    hbuf[0][r][k] = (__bf16)h0[(row0 + r) * Hn + k];
  }
  for (int idx = tid; idx < 2 * 8 * 136; idx += 576) {  // zero rows 8-15, both bufs
    int pr = idx / (8 * 136), rem = idx - pr * (8 * 136);
    hbuf[pr][8 + rem / 136][rem % 136] = (__bf16)0.f;
  }

  // weight fragments: branch-exclusive union (cores: W_hh[4][4]; wave8: W_lin[2][4])
  bf16x8 wreg[4][4];
  float  creg[4];
  float  bias0 = 0.f, bias1 = 0.f, mloc = 0.f;
  if (w < 8) {
#pragma unroll
    for (int g = 0; g < 4; ++g)
#pragma unroll
      for (int kt = 0; kt < 4; ++kt)
        wreg[g][kt] = __builtin_bit_cast(
            bf16x8, *(const uint4*)(wf + (((w * 4 + g) * 4 + kt) * 64 + l) * 8));
    if (quad < 2) {
#pragma unroll
      for (int p = 0; p < 4; ++p)
        creg[p] = c0[(row0 + quad * 4 + p) * Hn + kh];
    }
    if (w == 7) {  // block-local mask sum: 8 rows x 128 = 256 float4
      float s = 0.f;
      const float4* m4 = (const float4*)(maskY + row0 * Tn);
#pragma unroll
      for (int i = 0; i < 4; ++i) s += m4[l + i * 64].x + m4[l + i * 64].y +
                                       m4[l + i * 64].z + m4[l + i * 64].w;
      mloc = s;
    }
  } else {
#pragma unroll
    for (int n = 0; n < 2; ++n)
#pragma unroll
      for (int kt = 0; kt < 4; ++kt)
        wreg[n][kt] = __builtin_bit_cast(
            bf16x8, *(const uint4*)(wlf + ((n * 4 + kt) * 64 + l) * 8));
    bias0 = b_lin[lc];
    bias1 = (lc < Vn - 16) ? b_lin[lc + 16] : -1e30f;
  }
  float ce_acc = 0.f;
  __syncthreads();

  for (int t = 0; t < Tn; ++t) {  // cores act t<127, wave8 acts t>=1
    const int par = t & 1;
    const __bf16* hc = &hbuf[par][0][0];
    __bf16*       hn = &hbuf[par ^ 1][0][0];

    if (w < 8) {
      if (t < Tn - 1) {
        // Xproj gather (quads 0-1 hold the valid C-rows); issued first
        f32x4 acc[4] = {{0,0,0,0},{0,0,0,0},{0,0,0,0},{0,0,0,0}};
        if (quad < 2) {
#pragma unroll
          for (int p = 0; p < 4; ++p) {
            float4 x = X4[tokL[(quad * 4 + p) * 129 + t] * 128 + kh];
            acc[0][p] = x.x; acc[1][p] = x.y; acc[2][p] = x.z; acc[3][p] = x.w;
          }
        }
        bf16x8 af[4];
#pragma unroll
        for (int kt = 0; kt < 4; ++kt)
          af[kt] = __builtin_bit_cast(
              bf16x8, *(const uint4*)(hc + lc * 136 + kt * 32 + quad * 8));
#pragma unroll
        for (int g = 0; g < 4; ++g)
#pragma unroll
          for (int kt = 0; kt < 4; ++kt)
            acc[g] = __builtin_amdgcn_mfma_f32_16x16x32_bf16(af[kt], wreg[g][kt], acc[g], 0, 0, 0);

        if (quad < 2) {
#pragma unroll
          for (int p = 0; p < 4; ++p) {
            float c2 = sigf(acc[1][p]) * creg[p] + sigf(acc[0][p]) * tanh_(acc[2][p]);
            float h2 = sigf(acc[3][p]) * tanh_(c2);
            creg[p] = c2;
            hn[(quad * 4 + p) * 136 + kh] = (__bf16)h2;
          }
        }
      }
    } else if (t >= 1) {
      // logits of h(t) -> CE for ref-step t-1; targets tok[:,t], mask[:,t-1]
      bf16x8 af[4];
#pragma unroll
      for (int kt = 0; kt < 4; ++kt)
        af[kt] = __builtin_bit_cast(
            bf16x8, *(const uint4*)(hc + lc * 136 + kt * 32 + quad * 8));
      f32x4 lacc[2] = {{bias0, bias0, bias0, bias0}, {bias1, bias1, bias1, bias1}};
#pragma unroll
      for (int kt = 0; kt < 4; ++kt) {
        lacc[0] = __builtin_amdgcn_mfma_f32_16x16x32_bf16(af[kt], wreg[0][kt], lacc[0], 0, 0, 0);
        lacc[1] = __builtin_amdgcn_mfma_f32_16x16x32_bf16(af[kt], wreg[1][kt], lacc[1], 0, 0, 0);
      }
      if (quad < 2) {
#pragma unroll
        for (int p = 0; p < 4; ++p) {
          logits[(quad * 4 + p) * 36 + lc]      = lacc[0][p];
          logits[(quad * 4 + p) * 36 + 16 + lc] = lacc[1][p];
        }
      }
      // transpose-softmax: lanes 0-31, 4 lanes/row, 8 logits each, 2 shfl rounds
      if (l < 32) {
        int row = l >> 2, j = l & 3;
        float4 v0 = *(const float4*)(logits + row * 36 + j * 8);
        float4 v1 = *(const float4*)(logits + row * 36 + j * 8 + 4);
        float m = fmaxf(fmaxf(fmaxf(v0.x, v0.y), fmaxf(v0.z, v0.w)),
                        fmaxf(fmaxf(v1.x, v1.y), fmaxf(v1.z, v1.w)));
        m = fmaxf(m, __shfl_xor(m, 1));
        m = fmaxf(m, __shfl_xor(m, 2));
        float e = fexp2((v0.x - m) * 1.44269504f) + fexp2((v0.y - m) * 1.44269504f) +
                  fexp2((v0.z - m) * 1.44269504f) + fexp2((v0.w - m) * 1.44269504f) +
                  fexp2((v1.x - m) * 1.44269504f) + fexp2((v1.y - m) * 1.44269504f) +
                  fexp2((v1.z - m) * 1.44269504f) + fexp2((v1.w - m) * 1.44269504f);
        e += __shfl_xor(e, 1);
        e += __shfl_xor(e, 2);
        if (j == 0) {
          int   y  = tokL[row * 129 + t];
          float ly = logits[row * 36 + y];
          float ce = (m + __logf(e)) - ly;
          ce_acc += ce * maskL[row * 132 + t - 1];
        }
      }
    }
    __syncthreads();  // the only barrier per step
  }

  // final reductions: wave 7 mask partial -> LDS; wave 8 reduces CE + finishes
  if (w == 7) {
#pragma unroll
    for (int off = 32; off > 0; off >>= 1) mloc += __shfl_down(mloc, off);
    if (l == 0) red[0] = mloc;
  }
  __syncthreads();
  if (w == 8) {
#pragma unroll
    for (int off = 32; off > 0; off >>= 1) ce_acc += __shfl_down(ce_acc, off);
    if (l == 0) {
      atomicAdd(ws + WS_LOSS, ce_acc);
      atomicAdd(ws + WS_MASK, red[0]);
      __threadfence();
      unsigned old = atomicAdd((unsigned*)(ws + WS_CNT), 1u);
      if (old == NBLK - 1) {  // last block publishes
        float lv  = atomicAdd(ws + WS_LOSS, 0.f);
        float mv2 = atomicAdd(ws + WS_MASK, 0.f);
        out[0] = lv / mv2;
      }
    }
  }
}

extern "C" void kernel_launch(void* const* d_in, const int* in_sizes, int n_in,
                              void* d_out, int out_size, void* d_ws, size_t ws_size,
                              hipStream_t stream) {
  const int*   inpt  = (const int*)  d_in[0];
  const float* h0    = (const float*)d_in[1];
  const float* c0    = (const float*)d_in[2];
  const float* maskY = (const float*)d_in[3];
  // d_in[4] = beta (unused)
  const float* emb   = (const float*)d_in[5];
  const float* W_ih  = (const float*)d_in[6];
  const float* b_ih  = (const float*)d_in[7];
  const float* W_hh  = (const float*)d_in[8];
  const float* b_hh  = (const float*)d_in[9];
  const float* W_lin = (const float*)d_in[10];
  const float* b_lin = (const float*)d_in[11];
  float* ws  = (float*)d_ws;
  float* out = (float*)d_out;

  hipLaunchKernelGGL(k_setup, dim3(94),   dim3(256), 0, stream,
                     emb, W_ih, b_ih, b_hh, W_hh, W_lin, ws);
  hipLaunchKernelGGL(k_main,  dim3(NBLK), dim3(576), 0, stream,
                     inpt, h0, c0, maskY, b_lin, ws, out);
}